// Round 6
// baseline (201.332 us; speedup 1.0000x reference)
//
#include <hip/hip_runtime.h>
#include <stdint.h>
#include <math.h>

typedef int i32x4 __attribute__((ext_vector_type(4)));
typedef float f32x4 __attribute__((ext_vector_type(4)));

__device__ __forceinline__ void gload_lds16(const void* g, void* l) {
    __builtin_amdgcn_global_load_lds(
        (const __attribute__((address_space(1))) void*)(g),
        (__attribute__((address_space(3))) void*)(l), 16, 0, 0);
}

// ---------------------------------------------------------------------------
// int8 symmetric group-wise quant, group 128 along contiguous axis.
// 32 lanes per group, one float4 per lane. Writes PACKED i8 q-values and the
// per-group f32 scale (layout sT[row][K/128], group-minor).
// Uses true IEEE division x/scale to match np/jnp rounding exactly.
// ---------------------------------------------------------------------------
__global__ __launch_bounds__(256) void quant_i8_kernel(
    const float* __restrict__ in, signed char* __restrict__ qout,
    float* __restrict__ sT, long long n, int K) {
    long long t = (long long)blockIdx.x * 256 + threadIdx.x;
    long long base = t * 4;
    if (base >= n) return;
    const float4 v = *reinterpret_cast<const float4*>(in + base);
    float m = fmaxf(fmaxf(fabsf(v.x), fabsf(v.y)),
                    fmaxf(fabsf(v.z), fabsf(v.w)));
#pragma unroll
    for (int off = 1; off <= 16; off <<= 1)
        m = fmaxf(m, __shfl_xor(m, off, 64));
    const float scale = fmaxf(m / 127.0f, 1e-8f);
    const int q0 = (int)fminf(fmaxf(rintf(v.x / scale), -128.0f), 127.0f);
    const int q1 = (int)fminf(fmaxf(rintf(v.y / scale), -128.0f), 127.0f);
    const int q2 = (int)fminf(fmaxf(rintf(v.z / scale), -128.0f), 127.0f);
    const int q3 = (int)fminf(fmaxf(rintf(v.w / scale), -128.0f), 127.0f);
    const unsigned pack = (unsigned)(q0 & 255) | ((unsigned)(q1 & 255) << 8) |
                          ((unsigned)(q2 & 255) << 16) |
                          ((unsigned)(q3 & 255) << 24);
    reinterpret_cast<unsigned*>(qout)[t] = pack;
    if ((threadIdx.x & 31) == 0) {
        const long long row = base / K;
        const int g = (int)((base % K) >> 7);
        sT[row * (K >> 7) + g] = scale;
    }
}

// ---------------------------------------------------------------------------
// Exact int8 GEMM with per-128-group dequant.
// C[M][N] = sum_g sx[r][g]*sw[c][g] * (sum_{k in g} qA[r][k]*qB[c][k])
// Tile 256(M) x 128(N), 8 waves (4M x 2N), wave tile 64x64.
// BK=64 i8 -> one mfma_i32_16x16x64_i8 per (m,n) frag per K-tile; group=128
// = 2 K-tiles: even tile MFMAs use C=0 (implicit acc reset), odd tile
// accumulates then flushes i32 -> f32 with sx*sw.
// Ring-4 LDS (A 16KB + B 8KB per slot = 96KB) + scale slabs (sx 16KB +
// sw 8KB, transposed [g][row] for conflict-free b128/b32 reads) = 120KB.
// vmcnt ledger: 3 staging loads per K-tile (A=2, B=1), depth 3. At body kt
// top, outstanding = kt(3)+kt+1(3)+kt+2(3)=9 -> vmcnt(6) drains kt exactly;
// stage(kt+3) issues after the barrier. Tail: NT-2 -> 3, NT-1 -> 0.
// Scale-slab reads are LDS (lgkm) -> never pollute the vmcnt ledger.
// WAR: stage(kt+3) targets slot (kt-1)&3; all reads of it were lgkm-consumed
// by MFMAs before each wave arrived at the body-kt barrier -> safe.
// Swizzle (64B rows): colbyte ^ (((row>>1)&3)<<4), pre-swizzled global
// source + swizzled read address (both-sides rule). Round-4-verified: 0
// bank conflicts with this exact geometry.
// ---------------------------------------------------------------------------
#define BM 256
#define BN 128
#define BKT 64

#define LDS_RING 0          // 4 slots x 24KB
#define LDS_SX 98304        // [16][256] f32, 16KB
#define LDS_SW 114688       // [16][128] f32, 8KB
#define LDS_TOTAL 122880

__device__ __forceinline__ void stageA_i8(const signed char* __restrict__ G,
                                          char* L, int tid, int baseRow, int K,
                                          int k0) {
    // A tile [256][64] i8 = 16KB: 2 calls x 512 thr x 16B.
    const int srow = tid >> 2;
    const int scb = ((tid & 3) << 4) ^ (((srow >> 1) & 3) << 4);
#pragma unroll
    for (int i = 0; i < 2; ++i)
        gload_lds16(G + (size_t)(baseRow + i * 128 + srow) * K + k0 + scb,
                    L + i * 8192 + (tid >> 6) * 1024);
}

__device__ __forceinline__ void stageB_i8(const signed char* __restrict__ G,
                                          char* L, int tid, int baseRow, int K,
                                          int k0) {
    // B tile [128][64] i8 = 8KB: 1 call.
    const int srow = tid >> 2;
    const int scb = ((tid & 3) << 4) ^ (((srow >> 1) & 3) << 4);
    gload_lds16(G + (size_t)(baseRow + srow) * K + k0 + scb,
                L + (tid >> 6) * 1024);
}

#define MFMA_I8(a, b, c) __builtin_amdgcn_mfma_i32_16x16x64_i8(a, b, c, 0, 0, 0)
#define LDFA(m) (*(const i32x4*)(Ab + (((ra + (m)*16) << 6) + coe)))
#define LDFB(n) (*(const i32x4*)(Bb + (((rb + (n)*16) << 6) + coe)))

__global__ __launch_bounds__(512, 2) void gemm_i8_group(
    const signed char* __restrict__ A,  // [M][K] i8
    const signed char* __restrict__ B,  // [N][K] i8
    const float* __restrict__ SX,       // [M][K/128] f32 (group-minor)
    const float* __restrict__ SW,       // [N][K/128] f32
    float* __restrict__ C,              // [M][N]
    int M, int N, int K) {
    __shared__ __align__(16) char smem[LDS_TOTAL];

    const int tid = threadIdx.x;
    const int lane = tid & 63;
    const int wid = tid >> 6;
    const int wr = wid >> 1;   // 0..3 (M quarter)
    const int wc = wid & 1;    // 0..1 (N half)
    const int l15 = lane & 15;
    const int lh = lane >> 4;  // 0..3 = 16-byte k-chunk
    const int coe = (lh << 4) ^ (((l15 >> 1) & 3) << 4);
    const int ra = wr * 64 + l15;  // + m*16  (A row in tile)
    const int rb = wc * 64 + l15;  // + n*16  (B row in tile)
    const int GP = K >> 7;         // groups = 16

    // XCD-chunked bijective remap over 1024 blocks (1024 % 8 == 0).
    const int id = (blockIdx.x & 7) * 128 + (blockIdx.x >> 3);
    const int tileM = (id >> 4) * BM;   // 64 M-tiles
    const int tileN = (id & 15) * BN;   // 16 N-tiles

    const int NT = K >> 6;  // 32 K-tiles of 64

    // ---- prologue: load scale slabs (normal loads), stage tiles 0..2 ----
    // sx transpose: [row][g] global -> [g][row] LDS. 512 thr x 8 vals.
    const int sxcol = tid & 255;          // tile row 0..255
    const int sxgb = (tid >> 8) * 8;      // g block 0 or 8
    f32x4 sxv0 = *(const f32x4*)(SX + (size_t)(tileM + sxcol) * GP + sxgb);
    f32x4 sxv1 = *(const f32x4*)(SX + (size_t)(tileM + sxcol) * GP + sxgb + 4);
    // sw transpose: 512 thr x 4 vals.
    const int swcol = tid & 127;
    const int swgb = (tid >> 7) * 4;
    f32x4 swv0 = *(const f32x4*)(SW + (size_t)(tileN + swcol) * GP + swgb);

    stageA_i8(A, smem, tid, tileM, K, 0);
    stageB_i8(B, smem + 16384, tid, tileN, K, 0);
    stageA_i8(A, smem + 24576, tid, tileM, K, 64);
    stageB_i8(B, smem + 40960, tid, tileN, K, 64);
    stageA_i8(A, smem + 49152, tid, tileM, K, 128);
    stageB_i8(B, smem + 65536, tid, tileN, K, 128);

    {
        float* sxl = (float*)(smem + LDS_SX);
        float* swl = (float*)(smem + LDS_SW);
#pragma unroll
        for (int j = 0; j < 4; ++j) {
            sxl[(sxgb + j) * 256 + sxcol] = sxv0[j];
            sxl[(sxgb + 4 + j) * 256 + sxcol] = sxv1[j];
            swl[(swgb + j) * 128 + swcol] = swv0[j];
        }
    }
    asm volatile("s_waitcnt lgkmcnt(0)" ::: "memory");

    f32x4 accf[4][4] = {};
    i32x4 acci[4][4] = {};
    const i32x4 zi = {0, 0, 0, 0};

#pragma unroll 1
    for (int kt = 0; kt < NT; ++kt) {
        // counted vmcnt: drain tile kt's 3 staging loads.
        if (kt < NT - 2)
            asm volatile("s_waitcnt vmcnt(6)" ::: "memory");
        else if (kt == NT - 2)
            asm volatile("s_waitcnt vmcnt(3)" ::: "memory");
        else
            asm volatile("s_waitcnt vmcnt(0)" ::: "memory");
        __builtin_amdgcn_s_barrier();
        __builtin_amdgcn_sched_barrier(0);

        if (kt + 3 < NT) {
            char* slot = smem + ((kt + 3) & 3) * 24576;
            stageA_i8(A, slot, tid, tileM, K, (kt + 3) << 6);
            stageB_i8(B, slot + 16384, tid, tileN, K, (kt + 3) << 6);
        }

        const char* Ab = smem + (kt & 3) * 24576;
        const char* Bb = Ab + 16384;
        i32x4 a0 = LDFA(0), a1 = LDFA(1), a2 = LDFA(2), a3 = LDFA(3);
        i32x4 b0 = LDFB(0), b1 = LDFB(1), b2 = LDFB(2), b3 = LDFB(3);

        __builtin_amdgcn_s_setprio(1);
        if ((kt & 1) == 0) {  // first half of group: fresh accumulators
            acci[0][0] = MFMA_I8(a0, b0, zi); acci[0][1] = MFMA_I8(a0, b1, zi);
            acci[0][2] = MFMA_I8(a0, b2, zi); acci[0][3] = MFMA_I8(a0, b3, zi);
            acci[1][0] = MFMA_I8(a1, b0, zi); acci[1][1] = MFMA_I8(a1, b1, zi);
            acci[1][2] = MFMA_I8(a1, b2, zi); acci[1][3] = MFMA_I8(a1, b3, zi);
            acci[2][0] = MFMA_I8(a2, b0, zi); acci[2][1] = MFMA_I8(a2, b1, zi);
            acci[2][2] = MFMA_I8(a2, b2, zi); acci[2][3] = MFMA_I8(a2, b3, zi);
            acci[3][0] = MFMA_I8(a3, b0, zi); acci[3][1] = MFMA_I8(a3, b1, zi);
            acci[3][2] = MFMA_I8(a3, b2, zi); acci[3][3] = MFMA_I8(a3, b3, zi);
            __builtin_amdgcn_s_setprio(0);
        } else {  // second half of group: accumulate, then flush
#pragma unroll
            for (int m = 0; m < 4; ++m) {
                acci[m][0] = MFMA_I8((m == 0 ? a0 : m == 1 ? a1 : m == 2 ? a2 : a3), b0, acci[m][0]);
                acci[m][1] = MFMA_I8((m == 0 ? a0 : m == 1 ? a1 : m == 2 ? a2 : a3), b1, acci[m][1]);
                acci[m][2] = MFMA_I8((m == 0 ? a0 : m == 1 ? a1 : m == 2 ? a2 : a3), b2, acci[m][2]);
                acci[m][3] = MFMA_I8((m == 0 ? a0 : m == 1 ? a1 : m == 2 ? a2 : a3), b3, acci[m][3]);
            }
            __builtin_amdgcn_s_setprio(0);
            // ---- flush group g = kt>>1: f32 += i32 * (sx[row]*sw[col]) ----
            const int g = kt >> 1;
            const float* sxl =
                (const float*)(smem + LDS_SX) + g * 256 + wr * 64 + lh * 4;
            const float* swl =
                (const float*)(smem + LDS_SW) + g * 128 + wc * 64 + l15;
            f32x4 sxq[4];
            float swq[4];
#pragma unroll
            for (int m = 0; m < 4; ++m) sxq[m] = *(const f32x4*)(sxl + m * 16);
#pragma unroll
            for (int n = 0; n < 4; ++n) swq[n] = swl[n * 16];
#pragma unroll
            for (int m = 0; m < 4; ++m)
#pragma unroll
                for (int n = 0; n < 4; ++n)
#pragma unroll
                    for (int r = 0; r < 4; ++r)
                        accf[m][n][r] += (float)acci[m][n][r] *
                                         (sxq[m][r] * swq[n]);
        }
    }

    // ---- epilogue: C/D layout col = lane&15, row = (lane>>4)*4 + reg ----
    const int c0 = tileN + wc * 64 + l15;
    const int r0 = tileM + wr * 64 + lh * 4;
#pragma unroll
    for (int m = 0; m < 4; ++m)
#pragma unroll
        for (int n = 0; n < 4; ++n)
#pragma unroll
            for (int r = 0; r < 4; ++r)
                C[(size_t)(r0 + m * 16 + r) * N + (c0 + n * 16)] =
                    accf[m][n][r];
}

// ---------------------------------------------------------------------------
extern "C" void kernel_launch(void* const* d_in, const int* in_sizes, int n_in,
                              void* d_out, int out_size, void* d_ws,
                              size_t ws_size, hipStream_t stream) {
    const float* x = (const float*)d_in[0];  // [B,S,IN]  f32
    const float* w = (const float*)d_in[1];  // [OUT,IN]  f32
    float* out = (float*)d_out;              // [B,S,OUT] f32

    const long long MK = (long long)in_sizes[0];
    const long long NK = (long long)in_sizes[1];
    const long long MN = (long long)out_size;
    const long long K =
        (long long)(sqrt((double)MK * (double)NK / (double)MN) + 0.5);
    const long long M = MK / K;  // 16384
    const long long N = NK / K;  // 2048
    const long long GP = K >> 7; // 16

    signed char* qx = (signed char*)d_ws;            // MK i8
    signed char* qw = qx + MK;                       // NK i8
    float* sx = (float*)(qx + MK + NK);              // M*GP f32
    float* sw = sx + M * GP;                         // N*GP f32

    quant_i8_kernel<<<(int)(MK / 1024), 256, 0, stream>>>(x, qx, sx, MK,
                                                          (int)K);
    quant_i8_kernel<<<(int)(NK / 1024), 256, 0, stream>>>(w, qw, sw, NK,
                                                          (int)K);

    dim3 grid((int)((M / BM) * (N / BN)));  // 64*16 = 1024
    gemm_i8_group<<<grid, 512, 0, stream>>>(qx, qw, sx, sw, out, (int)M,
                                            (int)N, (int)K);
}

// Round 7
// 184.252 us; speedup vs baseline: 1.0927x; 1.0927x over previous
//
#include <hip/hip_runtime.h>
#include <stdint.h>
#include <math.h>

typedef __bf16 bf16x8 __attribute__((ext_vector_type(8)));
typedef float f32x4 __attribute__((ext_vector_type(4)));
typedef unsigned short u16x8 __attribute__((ext_vector_type(8)));

__device__ __forceinline__ unsigned short f32_to_bf16_rne(float f) {
    unsigned u = __builtin_bit_cast(unsigned, f);
    u += 0x7fffu + ((u >> 16) & 1u);
    return (unsigned short)(u >> 16);
}

// ---------------------------------------------------------------------------
// int8 symmetric group-wise fake-quant, group 128 along contiguous axis.
// 32 lanes per group, one float4 per lane. Output = bf16(q*scale).
// At HBM BW roofline — unchanged from round 4.
// ---------------------------------------------------------------------------
__global__ __launch_bounds__(256) void quant_fake_int8_kernel(
    const float* __restrict__ in, unsigned short* __restrict__ out,
    long long n) {
    long long t = (long long)blockIdx.x * 256 + threadIdx.x;
    long long base = t * 4;
    if (base >= n) return;
    const float4 v = *reinterpret_cast<const float4*>(in + base);
    float m = fmaxf(fmaxf(fabsf(v.x), fabsf(v.y)),
                    fmaxf(fabsf(v.z), fabsf(v.w)));
#pragma unroll
    for (int off = 1; off <= 16; off <<= 1)
        m = fmaxf(m, __shfl_xor(m, off, 64));
    const float scale = fmaxf(m / 127.0f, 1e-8f);
    const float d0 = fminf(fmaxf(rintf(v.x / scale), -128.0f), 127.0f) * scale;
    const float d1 = fminf(fmaxf(rintf(v.y / scale), -128.0f), 127.0f) * scale;
    const float d2 = fminf(fmaxf(rintf(v.z / scale), -128.0f), 127.0f) * scale;
    const float d3 = fminf(fmaxf(rintf(v.w / scale), -128.0f), 127.0f) * scale;
    ushort4 o;
    o.x = f32_to_bf16_rne(d0);
    o.y = f32_to_bf16_rne(d1);
    o.z = f32_to_bf16_rne(d2);
    o.w = f32_to_bf16_rne(d3);
    *reinterpret_cast<ushort4*>(out + base) = o;
}

// ---------------------------------------------------------------------------
// 256(M) x 128(N) bf16 GEMM, BK=32, ring-3 LDS (72 KB -> 2 blocks/CU),
// depth-2 prefetch, counted vmcnt. C[M][N] = A[M][K] * B[N][K]^T.
// 256 thr = 4 waves (2M x 2N), wave tile 128x64 -> 32 MFMA + 12 ds_read_b128
// per K-tile per wave (384 B fragment reads per MFMA — round-4 economy).
// TWO blocks per CU = two independent barrier domains: one block's read
// window overlaps the other block's MFMA window (m114 mechanism).
//
// LDS slot = A[256][32] (16 KB) + B[128][32] (8 KB) = 24 KB; ring 3 = 72 KB.
// vmcnt ledger (6 staging loads per K-tile: A=4, B=2, depth 2):
//   top of body kt: outstanding = kt(6) + kt+1(6) = 12 -> vmcnt(6) drains
//   kt exactly; stage(kt+2) issues after the barrier. kt=NT-1 -> vmcnt(0).
// WAR: stage(kt+2) writes slot (kt+2)%3 = (kt-1)%3, whose ds_reads were
// lgkm-consumed by each wave's MFMAs before it reached barrier kt -> safe.
// Swizzle (64B rows): colbyte ^ (((row>>1)&3)<<4), pre-swizzled global
// source + swizzled read address (both-sides rule). Verified 0 conflicts
// (rounds 4-6).
// ---------------------------------------------------------------------------
#define BM 256
#define BN 128
#define BKT 32
#define SLOT_ELEMS 12288  // 24 KB in bf16 elems; A at 0, B at 8192

__device__ __forceinline__ void gload16(const unsigned short* g,
                                        unsigned short* l) {
    __builtin_amdgcn_global_load_lds(
        (const __attribute__((address_space(1))) void*)(g),
        (__attribute__((address_space(3))) void*)(l), 16, 0, 0);
}

__device__ __forceinline__ void stageA(const unsigned short* __restrict__ G,
                                       unsigned short* L, int tid, int baseRow,
                                       int K, int k0) {
    // A tile [256][32] bf16 = 16 KB: 4 calls x 256 thr x 16 B.
    const int r = tid >> 2;  // 0..63
    const int scb = (((tid & 3) << 4) ^ (((r >> 1) & 3) << 4)) >> 1;
#pragma unroll
    for (int i = 0; i < 4; ++i)
        gload16(G + (size_t)(baseRow + i * 64 + r) * K + k0 + scb,
                L + i * 2048 + (tid >> 6) * 512);
}

__device__ __forceinline__ void stageB(const unsigned short* __restrict__ G,
                                       unsigned short* L, int tid, int baseRow,
                                       int K, int k0) {
    // B tile [128][32] bf16 = 8 KB: 2 calls.
    const int r = tid >> 2;
    const int scb = (((tid & 3) << 4) ^ (((r >> 1) & 3) << 4)) >> 1;
#pragma unroll
    for (int i = 0; i < 2; ++i)
        gload16(G + (size_t)(baseRow + i * 64 + r) * K + k0 + scb,
                L + i * 2048 + (tid >> 6) * 512);
}

#define LDF32(BASE, ROW)                                         \
    __builtin_bit_cast(bf16x8, *reinterpret_cast<const u16x8*>(  \
                                   (BASE) + (((ROW) << 5) + coe)))
#define MFMA(a, bb, c) __builtin_amdgcn_mfma_f32_16x16x32_bf16(a, bb, c, 0, 0, 0)

__global__ __launch_bounds__(256, 2) void gemm_bf16_r3(
    const unsigned short* __restrict__ A,  // [M][K] bf16 bits
    const unsigned short* __restrict__ B,  // [N][K] bf16 bits
    float* __restrict__ C,                 // [M][N]
    int M, int N, int K) {
    __shared__ __align__(16) unsigned short smem[3 * SLOT_ELEMS];  // 72 KB

    const int tid = threadIdx.x;
    const int lane = tid & 63;
    const int wid = tid >> 6;  // 0..3
    const int wr = wid >> 1;   // 0..1 (M half)
    const int wc = wid & 1;    // 0..1 (N half)
    const int l15 = lane & 15;
    const int lh = lane >> 4;  // 0..3 = 16B k-chunk
    const int coe = (((lh << 4) ^ (((l15 >> 1) & 3) << 4)) >> 1);
    const int ra = wr * 128 + l15;  // + m*16  (A row, 0..255)
    const int rb = wc * 64 + l15;   // + n*16  (B row, 0..127)

    // XCD-chunked bijective remap over 1024 blocks (1024 % 8 == 0).
    const int id = (blockIdx.x & 7) * 128 + (blockIdx.x >> 3);
    const int tileM = (id >> 4) * BM;  // 64 M-tiles
    const int tileN = (id & 15) * BN;  // 16 N-tiles

    const int NT = K >> 5;  // 64

    f32x4 acc[8][4] = {};

    // prologue: stage K-tiles 0,1 into slots 0,1 (12 loads outstanding)
    stageA(A, smem, tid, tileM, K, 0);
    stageB(B, smem + 8192, tid, tileN, K, 0);
    stageA(A, smem + SLOT_ELEMS, tid, tileM, K, 32);
    stageB(B, smem + SLOT_ELEMS + 8192, tid, tileN, K, 32);

    int cs = 0;  // slot of current tile kt
#pragma unroll 1
    for (int kt = 0; kt < NT; ++kt) {
        if (kt < NT - 1)
            asm volatile("s_waitcnt vmcnt(6)" ::: "memory");
        else
            asm volatile("s_waitcnt vmcnt(0)" ::: "memory");
        __builtin_amdgcn_s_barrier();  // slot cs visible to all 4 waves
        __builtin_amdgcn_sched_barrier(0);

        if (kt + 2 < NT) {
            int ws = cs + 2;
            if (ws >= 3) ws -= 3;  // slot of kt+2
            unsigned short* slot = smem + ws * SLOT_ELEMS;
            stageA(A, slot, tid, tileM, K, (kt + 2) << 5);
            stageB(B, slot + 8192, tid, tileN, K, (kt + 2) << 5);
        }

        const unsigned short* Ab = smem + cs * SLOT_ELEMS;
        const unsigned short* Bb = Ab + 8192;
        bf16x8 a0 = LDF32(Ab, ra + 0), a1 = LDF32(Ab, ra + 16);
        bf16x8 a2 = LDF32(Ab, ra + 32), a3 = LDF32(Ab, ra + 48);
        bf16x8 a4 = LDF32(Ab, ra + 64), a5 = LDF32(Ab, ra + 80);
        bf16x8 a6 = LDF32(Ab, ra + 96), a7 = LDF32(Ab, ra + 112);
        bf16x8 b0 = LDF32(Bb, rb + 0), b1 = LDF32(Bb, rb + 16);
        bf16x8 b2 = LDF32(Bb, rb + 32), b3 = LDF32(Bb, rb + 48);

        __builtin_amdgcn_s_setprio(1);
#pragma unroll
        for (int n = 0; n < 4; ++n) {
            const bf16x8 bn = (n == 0) ? b0 : (n == 1) ? b1 : (n == 2) ? b2 : b3;
            acc[0][n] = MFMA(a0, bn, acc[0][n]);
            acc[1][n] = MFMA(a1, bn, acc[1][n]);
            acc[2][n] = MFMA(a2, bn, acc[2][n]);
            acc[3][n] = MFMA(a3, bn, acc[3][n]);
            acc[4][n] = MFMA(a4, bn, acc[4][n]);
            acc[5][n] = MFMA(a5, bn, acc[5][n]);
            acc[6][n] = MFMA(a6, bn, acc[6][n]);
            acc[7][n] = MFMA(a7, bn, acc[7][n]);
        }
        __builtin_amdgcn_s_setprio(0);

        cs = (cs == 2) ? 0 : cs + 1;
    }

    // ---- epilogue: C/D layout col = lane&15, row = (lane>>4)*4 + reg ----
    const int c0 = tileN + wc * 64 + l15;
    const int r0 = tileM + wr * 128 + lh * 4;
#pragma unroll
    for (int m = 0; m < 8; ++m)
#pragma unroll
        for (int n = 0; n < 4; ++n)
#pragma unroll
            for (int r = 0; r < 4; ++r)
                C[(size_t)(r0 + m * 16 + r) * N + (c0 + n * 16)] =
                    acc[m][n][r];
}

// ---------------------------------------------------------------------------
extern "C" void kernel_launch(void* const* d_in, const int* in_sizes, int n_in,
                              void* d_out, int out_size, void* d_ws,
                              size_t ws_size, hipStream_t stream) {
    const float* x = (const float*)d_in[0];  // [B,S,IN]  f32
    const float* w = (const float*)d_in[1];  // [OUT,IN]  f32
    float* out = (float*)d_out;              // [B,S,OUT] f32

    const long long MK = (long long)in_sizes[0];
    const long long NK = (long long)in_sizes[1];
    const long long MN = (long long)out_size;
    const long long K =
        (long long)(sqrt((double)MK * (double)NK / (double)MN) + 0.5);
    const long long M = MK / K;  // 16384
    const long long N = NK / K;  // 2048

    unsigned short* qx = (unsigned short*)d_ws;  // M*K bf16
    unsigned short* qw = qx + MK;                // N*K bf16

    quant_fake_int8_kernel<<<(int)(MK / 1024), 256, 0, stream>>>(x, qx, MK);
    quant_fake_int8_kernel<<<(int)(NK / 1024), 256, 0, stream>>>(w, qw, NK);

    dim3 grid((int)((M / BM) * (N / BN)));  // 64 * 16 = 1024
    gemm_bf16_r3<<<grid, 256, 0, stream>>>(qx, qw, out, (int)M, (int)N,
                                           (int)K);
}

// Round 8
// 179.241 us; speedup vs baseline: 1.1233x; 1.0280x over previous
//
#include <hip/hip_runtime.h>
#include <stdint.h>
#include <math.h>

typedef __bf16 bf16x8 __attribute__((ext_vector_type(8)));
typedef float f32x4 __attribute__((ext_vector_type(4)));
typedef unsigned short u16x8 __attribute__((ext_vector_type(8)));

__device__ __forceinline__ unsigned short f32_to_bf16_rne(float f) {
    unsigned u = __builtin_bit_cast(unsigned, f);
    u += 0x7fffu + ((u >> 16) & 1u);
    return (unsigned short)(u >> 16);
}

// ---------------------------------------------------------------------------
// int8 symmetric group-wise fake-quant, group 128 along contiguous axis.
// 32 lanes per group, one float4 per lane. Output = bf16(q*scale).
// At HBM BW roofline — unchanged.
// ---------------------------------------------------------------------------
__global__ __launch_bounds__(256) void quant_fake_int8_kernel(
    const float* __restrict__ in, unsigned short* __restrict__ out,
    long long n) {
    long long t = (long long)blockIdx.x * 256 + threadIdx.x;
    long long base = t * 4;
    if (base >= n) return;
    const float4 v = *reinterpret_cast<const float4*>(in + base);
    float m = fmaxf(fmaxf(fabsf(v.x), fabsf(v.y)),
                    fmaxf(fabsf(v.z), fabsf(v.w)));
#pragma unroll
    for (int off = 1; off <= 16; off <<= 1)
        m = fmaxf(m, __shfl_xor(m, off, 64));
    const float scale = fmaxf(m / 127.0f, 1e-8f);
    const float d0 = fminf(fmaxf(rintf(v.x / scale), -128.0f), 127.0f) * scale;
    const float d1 = fminf(fmaxf(rintf(v.y / scale), -128.0f), 127.0f) * scale;
    const float d2 = fminf(fmaxf(rintf(v.z / scale), -128.0f), 127.0f) * scale;
    const float d3 = fminf(fmaxf(rintf(v.w / scale), -128.0f), 127.0f) * scale;
    ushort4 o;
    o.x = f32_to_bf16_rne(d0);
    o.y = f32_to_bf16_rne(d1);
    o.z = f32_to_bf16_rne(d2);
    o.w = f32_to_bf16_rne(d3);
    *reinterpret_cast<ushort4*>(out + base) = o;
}

// ---------------------------------------------------------------------------
// 256x256 bf16 GEMM, BK=64, 4 fine phases per K-tile (m201 skeleton),
// A ring-3 + B dbuf-2 LDS (160 KB), counted vmcnt (never 0 mid-loop).
// C[M][N] = A[M][K] * B[N][K]^T.  512 thr = 8 waves (2M x 4N), wave 128x64.
//
// Phase p of tile kt = {ds_reads (8 or 4); stage 2 gloads; s_barrier;
//   lgkmcnt(0); sched_barrier; setprio(1); 16 MFMA; setprio(0); s_barrier}.
// Phases: p1 (kk0, m0-3 + all B[kk0]) / p2 (kk0, m4-7) /
//         p3 (kk1, m0-3 + all B[kk1]) / p4 (kk1, m4-7).
//
// Staging schedule during tile kt:  p1,p2 -> B(kt+1) halves (dbuf slot
// (kt+1)&1, its old contents last read in tile kt-1); p3,p4 -> A(kt+2)
// halves (ring slot (kt+2)%3, last read in tile kt-1). In-order VMEM queue
// entering kt's p4 wait: [A(kt+1) 4][B(kt+1) 4][A(kt+2) 4] -> vmcnt(4)
// drains exactly A(kt+1)+B(kt+1) (what tile kt+1 needs), keeps A(kt+2) in
// flight. Prologue: stage A0,B0,A1 (12 loads), vmcnt(4), barrier ->
// invariant holds at kt=0. Tail: kt+2>=NT -> vmcnt(0).
// WAR: every stage targets a slot whose readers all passed lgkmcnt(0)
// before the previous tile's final barrier -> race-free.
// Swizzle (128B rows): colbyte ^ ((row&7)<<4), pre-swizzled global source +
// swizzled read address (both-sides rule). Round-2-verified: 0 conflicts.
// ---------------------------------------------------------------------------
#define BM 256
#define BN 256
#define BKT 64
#define NSLOT 16384  // elems per 32 KB slot ([256][64] bf16)

__device__ __forceinline__ void gload16(const unsigned short* g,
                                        unsigned short* l) {
    __builtin_amdgcn_global_load_lds(
        (const __attribute__((address_space(1))) void*)(g),
        (__attribute__((address_space(3))) void*)(l), 16, 0, 0);
}

// Stage one half (rows h*128 .. h*128+127) of a [256][64] tile: 2 loads.
__device__ __forceinline__ void stage_half(const unsigned short* __restrict__ G,
                                           unsigned short* L, int tid,
                                           int baseRow, int K, int k0, int h) {
    const int srow = tid >> 3;                                   // 0..63
    const int scb = (((tid & 7) << 4) ^ ((srow & 7) << 4)) >> 1; // elem col
#pragma unroll
    for (int i = 2 * h; i < 2 * h + 2; ++i)
        gload16(G + (size_t)(baseRow + i * 64 + srow) * K + k0 + scb,
                L + i * 4096 + (tid >> 6) * 512);
}

#define LDF(BASE, ROW, COE)                                      \
    __builtin_bit_cast(bf16x8, *reinterpret_cast<const u16x8*>(  \
                                   (BASE) + (((ROW) << 6) + (COE))))
#define MFMA(a, bb, c) __builtin_amdgcn_mfma_f32_16x16x32_bf16(a, bb, c, 0, 0, 0)
#define LGKM0                                          \
    asm volatile("s_waitcnt lgkmcnt(0)" ::: "memory"); \
    __builtin_amdgcn_sched_barrier(0)

__global__ __launch_bounds__(512, 2) void gemm_bf16_4ph(
    const unsigned short* __restrict__ A,  // [M][K] bf16 bits
    const unsigned short* __restrict__ B,  // [N][K] bf16 bits
    float* __restrict__ C,                 // [M][N]
    int M, int N, int K) {
    __shared__ __align__(16) unsigned short smem[5 * NSLOT];  // 160 KB

    const int tid = threadIdx.x;
    const int lane = tid & 63;
    const int wid = tid >> 6;
    const int wr = wid >> 2;  // 0..1  (M half)
    const int wc = wid & 3;   // 0..3  (N quarter)
    const int l15 = lane & 15;
    const int lh = lane >> 4;
    const int swz = (lane & 7) << 4;
    const int coe0 = ((lh << 4) ^ swz) >> 1;        // kk=0 elem col
    const int coe1 = (((lh << 4) | 64) ^ swz) >> 1; // kk=1 elem col
    const int ra = wr * 128 + l15;                  // + m*16
    const int rb = wc * 64 + l15;                   // + n*16

    // XCD-chunked bijective remap over 512 blocks (512 % 8 == 0).
    const int id = (blockIdx.x & 7) * 64 + (blockIdx.x >> 3);
    const int tileN = (id & 7) * BN;
    const int tileM = (id >> 3) * BM;

    const int NT = K >> 6;  // 32

    f32x4 acc[8][4] = {};
    bf16x8 b[4];

    // ---- prologue: A0, B0, A1 (12 loads); drain A0+B0; keep A1 in flight.
    stage_half(A, smem + 0 * NSLOT, tid, tileM, K, 0, 0);
    stage_half(A, smem + 0 * NSLOT, tid, tileM, K, 0, 1);
    stage_half(B, smem + 3 * NSLOT, tid, tileN, K, 0, 0);
    stage_half(B, smem + 3 * NSLOT, tid, tileN, K, 0, 1);
    stage_half(A, smem + 1 * NSLOT, tid, tileM, K, 64, 0);
    stage_half(A, smem + 1 * NSLOT, tid, tileM, K, 64, 1);
    asm volatile("s_waitcnt vmcnt(4)" ::: "memory");
    __builtin_amdgcn_sched_barrier(0);
    __builtin_amdgcn_s_barrier();

    int aSlot = 0;  // ring slot of A(kt)
#pragma unroll 1
    for (int kt = 0; kt < NT; ++kt) {
        const unsigned short* Ab = smem + aSlot * NSLOT;
        const unsigned short* Bb = smem + (3 + (kt & 1)) * NSLOT;
        unsigned short* Bn = smem + (3 + ((kt + 1) & 1)) * NSLOT;
        int a2 = aSlot + 2;
        if (a2 >= 3) a2 -= 3;
        unsigned short* An = smem + a2 * NSLOT;
        const bool pfB = (kt + 1 < NT);
        const bool pfA = (kt + 2 < NT);

        // ---------- p1: kk0, m0-3 (+ all B[kk0]) ----------
        {
            bf16x8 a0 = LDF(Ab, ra + 0, coe0), a1 = LDF(Ab, ra + 16, coe0);
            bf16x8 a2f = LDF(Ab, ra + 32, coe0), a3 = LDF(Ab, ra + 48, coe0);
#pragma unroll
            for (int n = 0; n < 4; ++n) b[n] = LDF(Bb, rb + n * 16, coe0);
            if (pfB) stage_half(B, Bn, tid, tileN, K, (kt + 1) << 6, 0);
            __builtin_amdgcn_s_barrier();
            LGKM0;
            __builtin_amdgcn_s_setprio(1);
#pragma unroll
            for (int n = 0; n < 4; ++n) {
                acc[0][n] = MFMA(a0, b[n], acc[0][n]);
                acc[1][n] = MFMA(a1, b[n], acc[1][n]);
                acc[2][n] = MFMA(a2f, b[n], acc[2][n]);
                acc[3][n] = MFMA(a3, b[n], acc[3][n]);
            }
            __builtin_amdgcn_s_setprio(0);
            __builtin_amdgcn_s_barrier();
        }
        // ---------- p2: kk0, m4-7 ----------
        {
            bf16x8 a0 = LDF(Ab, ra + 64, coe0), a1 = LDF(Ab, ra + 80, coe0);
            bf16x8 a2f = LDF(Ab, ra + 96, coe0), a3 = LDF(Ab, ra + 112, coe0);
            if (pfB) stage_half(B, Bn, tid, tileN, K, (kt + 1) << 6, 1);
            __builtin_amdgcn_s_barrier();
            LGKM0;
            __builtin_amdgcn_s_setprio(1);
#pragma unroll
            for (int n = 0; n < 4; ++n) {
                acc[4][n] = MFMA(a0, b[n], acc[4][n]);
                acc[5][n] = MFMA(a1, b[n], acc[5][n]);
                acc[6][n] = MFMA(a2f, b[n], acc[6][n]);
                acc[7][n] = MFMA(a3, b[n], acc[7][n]);
            }
            __builtin_amdgcn_s_setprio(0);
            __builtin_amdgcn_s_barrier();
        }
        // ---------- p3: kk1, m0-3 (+ all B[kk1]) ----------
        {
            bf16x8 a0 = LDF(Ab, ra + 0, coe1), a1 = LDF(Ab, ra + 16, coe1);
            bf16x8 a2f = LDF(Ab, ra + 32, coe1), a3 = LDF(Ab, ra + 48, coe1);
#pragma unroll
            for (int n = 0; n < 4; ++n) b[n] = LDF(Bb, rb + n * 16, coe1);
            if (pfA) stage_half(A, An, tid, tileM, K, (kt + 2) << 6, 0);
            __builtin_amdgcn_s_barrier();
            LGKM0;
            __builtin_amdgcn_s_setprio(1);
#pragma unroll
            for (int n = 0; n < 4; ++n) {
                acc[0][n] = MFMA(a0, b[n], acc[0][n]);
                acc[1][n] = MFMA(a1, b[n], acc[1][n]);
                acc[2][n] = MFMA(a2f, b[n], acc[2][n]);
                acc[3][n] = MFMA(a3, b[n], acc[3][n]);
            }
            __builtin_amdgcn_s_setprio(0);
            __builtin_amdgcn_s_barrier();
        }
        // ---------- p4: kk1, m4-7 (+ boundary vmcnt) ----------
        {
            bf16x8 a0 = LDF(Ab, ra + 64, coe1), a1 = LDF(Ab, ra + 80, coe1);
            bf16x8 a2f = LDF(Ab, ra + 96, coe1), a3 = LDF(Ab, ra + 112, coe1);
            if (pfA) stage_half(A, An, tid, tileM, K, (kt + 2) << 6, 1);
            __builtin_amdgcn_s_barrier();
            LGKM0;
            __builtin_amdgcn_s_setprio(1);
#pragma unroll
            for (int n = 0; n < 4; ++n) {
                acc[4][n] = MFMA(a0, b[n], acc[4][n]);
                acc[5][n] = MFMA(a1, b[n], acc[5][n]);
                acc[6][n] = MFMA(a2f, b[n], acc[6][n]);
                acc[7][n] = MFMA(a3, b[n], acc[7][n]);
            }
            __builtin_amdgcn_s_setprio(0);
            if (pfA)
                asm volatile("s_waitcnt vmcnt(4)" ::: "memory");
            else
                asm volatile("s_waitcnt vmcnt(0)" ::: "memory");
            __builtin_amdgcn_sched_barrier(0);
            __builtin_amdgcn_s_barrier();
        }
        aSlot = (aSlot == 2) ? 0 : aSlot + 1;
    }

    // ---- epilogue: C/D layout col = lane&15, row = (lane>>4)*4 + reg ----
    const int c0 = tileN + wc * 64 + l15;
    const int r0 = tileM + wr * 128 + lh * 4;
#pragma unroll
    for (int m = 0; m < 8; ++m)
#pragma unroll
        for (int n = 0; n < 4; ++n)
#pragma unroll
            for (int r = 0; r < 4; ++r)
                C[(size_t)(r0 + m * 16 + r) * N + (c0 + n * 16)] =
                    acc[m][n][r];
}

// ---------------------------------------------------------------------------
extern "C" void kernel_launch(void* const* d_in, const int* in_sizes, int n_in,
                              void* d_out, int out_size, void* d_ws,
                              size_t ws_size, hipStream_t stream) {
    const float* x = (const float*)d_in[0];  // [B,S,IN]  f32
    const float* w = (const float*)d_in[1];  // [OUT,IN]  f32
    float* out = (float*)d_out;              // [B,S,OUT] f32

    const long long MK = (long long)in_sizes[0];
    const long long NK = (long long)in_sizes[1];
    const long long MN = (long long)out_size;
    const long long K =
        (long long)(sqrt((double)MK * (double)NK / (double)MN) + 0.5);
    const long long M = MK / K;  // 16384
    const long long N = NK / K;  // 2048

    unsigned short* qx = (unsigned short*)d_ws;  // M*K bf16
    unsigned short* qw = qx + MK;                // N*K bf16

    quant_fake_int8_kernel<<<(int)(MK / 1024), 256, 0, stream>>>(x, qx, MK);
    quant_fake_int8_kernel<<<(int)(NK / 1024), 256, 0, stream>>>(w, qw, NK);

    dim3 grid((int)((M / BM) * (N / BN)));  // 64 * 8 = 512
    gemm_bf16_4ph<<<grid, 512, 0, stream>>>(qx, qw, out, (int)M, (int)N,
                                            (int)K);
}

// Round 9
// 170.524 us; speedup vs baseline: 1.1807x; 1.0511x over previous
//
#include <hip/hip_runtime.h>
#include <stdint.h>
#include <math.h>

typedef __bf16 bf16x8 __attribute__((ext_vector_type(8)));
typedef float f32x4 __attribute__((ext_vector_type(4)));
typedef unsigned short u16x8 __attribute__((ext_vector_type(8)));

__device__ __forceinline__ unsigned short f32_to_bf16_rne(float f) {
    unsigned u = __builtin_bit_cast(unsigned, f);
    u += 0x7fffu + ((u >> 16) & 1u);
    return (unsigned short)(u >> 16);
}

// ---------------------------------------------------------------------------
// int8 symmetric group-wise fake-quant, group 128 along contiguous axis.
// 32 lanes per group, one float4 per lane. Output = bf16(q*scale).
// At HBM BW roofline — unchanged.
// ---------------------------------------------------------------------------
__global__ __launch_bounds__(256) void quant_fake_int8_kernel(
    const float* __restrict__ in, unsigned short* __restrict__ out,
    long long n) {
    long long t = (long long)blockIdx.x * 256 + threadIdx.x;
    long long base = t * 4;
    if (base >= n) return;
    const float4 v = *reinterpret_cast<const float4*>(in + base);
    float m = fmaxf(fmaxf(fabsf(v.x), fabsf(v.y)),
                    fmaxf(fabsf(v.z), fabsf(v.w)));
#pragma unroll
    for (int off = 1; off <= 16; off <<= 1)
        m = fmaxf(m, __shfl_xor(m, off, 64));
    const float scale = fmaxf(m / 127.0f, 1e-8f);
    const float d0 = fminf(fmaxf(rintf(v.x / scale), -128.0f), 127.0f) * scale;
    const float d1 = fminf(fmaxf(rintf(v.y / scale), -128.0f), 127.0f) * scale;
    const float d2 = fminf(fmaxf(rintf(v.z / scale), -128.0f), 127.0f) * scale;
    const float d3 = fminf(fmaxf(rintf(v.w / scale), -128.0f), 127.0f) * scale;
    ushort4 o;
    o.x = f32_to_bf16_rne(d0);
    o.y = f32_to_bf16_rne(d1);
    o.z = f32_to_bf16_rne(d2);
    o.w = f32_to_bf16_rne(d3);
    *reinterpret_cast<ushort4*>(out + base) = o;
}

// ---------------------------------------------------------------------------
// 256x256 bf16 GEMM, BK=64, QUADRANT phases with TAIL-ONLY barriers.
// C[M][N] = A[M][K] * B[N][K]^T. 512 thr = 8 waves (2M x 4N), wave 128x64.
//
// Per K-tile kt, 4 phases; phase = {ds_reads; stage 2 gloads; setprio(1);
// 16 MFMA (one C-quadrant, K=64); setprio(0); s_barrier}.  NO head barrier,
// NO asm lgkmcnt, NO sched_barrier: compiler emits fine-grained counted
// lgkm waits, so a wave's MFMAs start as operands land while other waves'
// reads still drain — fabric hides under matrix (bounded-skew overlap).
//   P1: read A(m0-3)x2kk [8] + B(n0-1)x2kk [4]; stage B(kt+1)h0; Q(m0-3,n0-1)
//   P2: read B(n2-3)x2kk [4];                   stage B(kt+1)h1; Q(m0-3,n2-3)
//   P3: read A(m4-7)x2kk [8];                   stage A(kt+2)h0; Q(m4-7,n2-3)
//   P4: (0 reads);                              stage A(kt+2)h1; Q(m4-7,n0-1)
//       then boundary vmcnt + tail barrier.
// Reads/tile/wave = 24 (minimal); B-frags live P1..P4, A-frags 2 phases.
//
// LDS: A ring-3 (3x32KB) + B dbuf-2 (2x32KB) = 160 KB, 1 block/CU.
// vmcnt ledger (2 gloads per stage_half, in-order queue): entering kt's
// boundary: [B(kt+1) 4][A(kt+2) 4] (A(kt+1) older, drained transitively) ->
// vmcnt(4) drains A(kt+1)+B(kt+1), keeps A(kt+2) in flight (4-phase slack).
// Prologue: A0,B0,A1 (12 loads) -> vmcnt(4). Tail: kt==NT-2 -> vmcnt(0).
// WAR audit (skew <= 1 phase, barriers every phase):
//   * stage B(kt+1) slot (kt+1)&1: last read = tile kt-1 P2 (>=3 barriers).
//   * stage A(kt+2) slot (kt+2)%3 = (kt-1)%3: last read = tile kt-1 P3
//     (>=4 barriers).  All staged slots disjoint from any in-flight reads.
// Swizzle (128B rows): colbyte ^ ((row&7)<<4) on pre-swizzled global source
// + swizzled read address (both-sides). Verified 0 conflicts (rounds 2,8).
// ---------------------------------------------------------------------------
#define BM 256
#define BN 256
#define NSLOT 16384  // elems per 32 KB slot ([256][64] bf16)

__device__ __forceinline__ void gload16(const unsigned short* g,
                                        unsigned short* l) {
    __builtin_amdgcn_global_load_lds(
        (const __attribute__((address_space(1))) void*)(g),
        (__attribute__((address_space(3))) void*)(l), 16, 0, 0);
}

// Stage one half (rows h*128 .. h*128+127) of a [256][64] tile: 2 loads.
__device__ __forceinline__ void stage_half(const unsigned short* __restrict__ G,
                                           unsigned short* L, int tid,
                                           int baseRow, int K, int k0, int h) {
    const int srow = tid >> 3;                                   // 0..63
    const int scb = (((tid & 7) << 4) ^ ((srow & 7) << 4)) >> 1; // elem col
#pragma unroll
    for (int i = 2 * h; i < 2 * h + 2; ++i)
        gload16(G + (size_t)(baseRow + i * 64 + srow) * K + k0 + scb,
                L + i * 4096 + (tid >> 6) * 512);
}

#define LDF(BASE, ROW, COE)                                      \
    __builtin_bit_cast(bf16x8, *reinterpret_cast<const u16x8*>(  \
                                   (BASE) + (((ROW) << 6) + (COE))))
#define MFMA(a, bb, c) __builtin_amdgcn_mfma_f32_16x16x32_bf16(a, bb, c, 0, 0, 0)

__global__ __launch_bounds__(512, 2) void gemm_bf16_quad(
    const unsigned short* __restrict__ A,  // [M][K] bf16 bits
    const unsigned short* __restrict__ B,  // [N][K] bf16 bits
    float* __restrict__ C,                 // [M][N]
    int M, int N, int K) {
    __shared__ __align__(16) unsigned short smem[5 * NSLOT];  // 160 KB

    const int tid = threadIdx.x;
    const int lane = tid & 63;
    const int wid = tid >> 6;
    const int wr = wid >> 2;  // 0..1  (M half)
    const int wc = wid & 3;   // 0..3  (N quarter)
    const int l15 = lane & 15;
    const int lh = lane >> 4;
    const int swz = (lane & 7) << 4;
    const int coe0 = ((lh << 4) ^ swz) >> 1;        // kk=0 elem col
    const int coe1 = (((lh << 4) | 64) ^ swz) >> 1; // kk=1 elem col
    const int ra = wr * 128 + l15;                  // + m*16
    const int rb = wc * 64 + l15;                   // + n*16

    // XCD-chunked bijective remap over 512 blocks (512 % 8 == 0).
    const int id = (blockIdx.x & 7) * 64 + (blockIdx.x >> 3);
    const int tileN = (id & 7) * BN;
    const int tileM = (id >> 3) * BM;

    const int NT = K >> 6;  // 32

    f32x4 acc[8][4] = {};

    // A-ring pointers (rotate each tile), B dbuf pointers (swap each tile).
    unsigned short* pa0 = smem + 0 * NSLOT;  // A(kt)
    unsigned short* pa1 = smem + 1 * NSLOT;  // A(kt+1)
    unsigned short* pa2 = smem + 2 * NSLOT;  // A(kt+2) staging target
    unsigned short* pb0 = smem + 3 * NSLOT;  // B(kt)
    unsigned short* pb1 = smem + 4 * NSLOT;  // B(kt+1) staging target

    // ---- prologue: A0, B0, A1 (12 loads); drain A0+B0; keep A1 in flight.
    stage_half(A, pa0, tid, tileM, K, 0, 0);
    stage_half(A, pa0, tid, tileM, K, 0, 1);
    stage_half(B, pb0, tid, tileN, K, 0, 0);
    stage_half(B, pb0, tid, tileN, K, 0, 1);
    stage_half(A, pa1, tid, tileM, K, 64, 0);
    stage_half(A, pa1, tid, tileM, K, 64, 1);
    asm volatile("s_waitcnt vmcnt(4)" ::: "memory");
    __builtin_amdgcn_s_barrier();

#pragma unroll 1
    for (int kt = 0; kt < NT; ++kt) {
        const unsigned short* Ab = pa0;
        const unsigned short* Bb = pb0;
        const int k1 = (kt + 1) << 6;
        const int k2 = (kt + 2) << 6;
        const bool pfB = (kt + 1 < NT);
        const bool pfA = (kt + 2 < NT);

        // ---------- P1: A m0-3 (both kk) + B n0-1 (both kk); Q(0,0) -------
        bf16x8 a00 = LDF(Ab, ra + 0, coe0), a10 = LDF(Ab, ra + 16, coe0);
        bf16x8 a20 = LDF(Ab, ra + 32, coe0), a30 = LDF(Ab, ra + 48, coe0);
        bf16x8 a01 = LDF(Ab, ra + 0, coe1), a11 = LDF(Ab, ra + 16, coe1);
        bf16x8 a21 = LDF(Ab, ra + 32, coe1), a31 = LDF(Ab, ra + 48, coe1);
        bf16x8 b00 = LDF(Bb, rb + 0, coe0), b10 = LDF(Bb, rb + 16, coe0);
        bf16x8 b01 = LDF(Bb, rb + 0, coe1), b11 = LDF(Bb, rb + 16, coe1);
        if (pfB) stage_half(B, pb1, tid, tileN, K, k1, 0);
        __builtin_amdgcn_s_setprio(1);
        acc[0][0] = MFMA(a01, b01, MFMA(a00, b00, acc[0][0]));
        acc[1][0] = MFMA(a11, b01, MFMA(a10, b00, acc[1][0]));
        acc[2][0] = MFMA(a21, b01, MFMA(a20, b00, acc[2][0]));
        acc[3][0] = MFMA(a31, b01, MFMA(a30, b00, acc[3][0]));
        acc[0][1] = MFMA(a01, b11, MFMA(a00, b10, acc[0][1]));
        acc[1][1] = MFMA(a11, b11, MFMA(a10, b10, acc[1][1]));
        acc[2][1] = MFMA(a21, b11, MFMA(a20, b10, acc[2][1]));
        acc[3][1] = MFMA(a31, b11, MFMA(a30, b10, acc[3][1]));
        __builtin_amdgcn_s_setprio(0);
        __builtin_amdgcn_s_barrier();

        // ---------- P2: B n2-3 (both kk); Q(0,1) --------------------------
        bf16x8 b20 = LDF(Bb, rb + 32, coe0), b30 = LDF(Bb, rb + 48, coe0);
        bf16x8 b21 = LDF(Bb, rb + 32, coe1), b31 = LDF(Bb, rb + 48, coe1);
        if (pfB) stage_half(B, pb1, tid, tileN, K, k1, 1);
        __builtin_amdgcn_s_setprio(1);
        acc[0][2] = MFMA(a01, b21, MFMA(a00, b20, acc[0][2]));
        acc[1][2] = MFMA(a11, b21, MFMA(a10, b20, acc[1][2]));
        acc[2][2] = MFMA(a21, b21, MFMA(a20, b20, acc[2][2]));
        acc[3][2] = MFMA(a31, b21, MFMA(a30, b20, acc[3][2]));
        acc[0][3] = MFMA(a01, b31, MFMA(a00, b30, acc[0][3]));
        acc[1][3] = MFMA(a11, b31, MFMA(a10, b30, acc[1][3]));
        acc[2][3] = MFMA(a21, b31, MFMA(a20, b30, acc[2][3]));
        acc[3][3] = MFMA(a31, b31, MFMA(a30, b30, acc[3][3]));
        __builtin_amdgcn_s_setprio(0);
        __builtin_amdgcn_s_barrier();

        // ---------- P3: A m4-7 (both kk); Q(1,1) --------------------------
        bf16x8 c00 = LDF(Ab, ra + 64, coe0), c10 = LDF(Ab, ra + 80, coe0);
        bf16x8 c20 = LDF(Ab, ra + 96, coe0), c30 = LDF(Ab, ra + 112, coe0);
        bf16x8 c01 = LDF(Ab, ra + 64, coe1), c11 = LDF(Ab, ra + 80, coe1);
        bf16x8 c21 = LDF(Ab, ra + 96, coe1), c31 = LDF(Ab, ra + 112, coe1);
        if (pfA) stage_half(A, pa2, tid, tileM, K, k2, 0);
        __builtin_amdgcn_s_setprio(1);
        acc[4][2] = MFMA(c01, b21, MFMA(c00, b20, acc[4][2]));
        acc[5][2] = MFMA(c11, b21, MFMA(c10, b20, acc[5][2]));
        acc[6][2] = MFMA(c21, b21, MFMA(c20, b20, acc[6][2]));
        acc[7][2] = MFMA(c31, b21, MFMA(c30, b20, acc[7][2]));
        acc[4][3] = MFMA(c01, b31, MFMA(c00, b30, acc[4][3]));
        acc[5][3] = MFMA(c11, b31, MFMA(c10, b30, acc[5][3]));
        acc[6][3] = MFMA(c21, b31, MFMA(c20, b30, acc[6][3]));
        acc[7][3] = MFMA(c31, b31, MFMA(c30, b30, acc[7][3]));
        __builtin_amdgcn_s_setprio(0);
        __builtin_amdgcn_s_barrier();

        // ---------- P4: 0 reads; Q(1,0); boundary vmcnt -------------------
        if (pfA) stage_half(A, pa2, tid, tileM, K, k2, 1);
        __builtin_amdgcn_s_setprio(1);
        acc[4][0] = MFMA(c01, b01, MFMA(c00, b00, acc[4][0]));
        acc[5][0] = MFMA(c11, b01, MFMA(c10, b00, acc[5][0]));
        acc[6][0] = MFMA(c21, b01, MFMA(c20, b00, acc[6][0]));
        acc[7][0] = MFMA(c31, b01, MFMA(c30, b00, acc[7][0]));
        acc[4][1] = MFMA(c01, b11, MFMA(c00, b10, acc[4][1]));
        acc[5][1] = MFMA(c11, b11, MFMA(c10, b10, acc[5][1]));
        acc[6][1] = MFMA(c21, b11, MFMA(c20, b10, acc[6][1]));
        acc[7][1] = MFMA(c31, b11, MFMA(c30, b10, acc[7][1]));
        __builtin_amdgcn_s_setprio(0);
        if (pfA)
            asm volatile("s_waitcnt vmcnt(4)" ::: "memory");
        else if (pfB)
            asm volatile("s_waitcnt vmcnt(0)" ::: "memory");
        __builtin_amdgcn_s_barrier();

        // rotate A ring, swap B dbuf
        unsigned short* t = pa0;
        pa0 = pa1;
        pa1 = pa2;
        pa2 = t;
        t = pb0;
        pb0 = pb1;
        pb1 = t;
    }

    // ---- epilogue: C/D layout col = lane&15, row = (lane>>4)*4 + reg ----
    const int c0 = tileN + wc * 64 + l15;
    const int r0 = tileM + wr * 128 + lh * 4;
#pragma unroll
    for (int m = 0; m < 8; ++m)
#pragma unroll
        for (int n = 0; n < 4; ++n)
#pragma unroll
            for (int r = 0; r < 4; ++r)
                C[(size_t)(r0 + m * 16 + r) * N + (c0 + n * 16)] =
                    acc[m][n][r];
}

// ---------------------------------------------------------------------------
extern "C" void kernel_launch(void* const* d_in, const int* in_sizes, int n_in,
                              void* d_out, int out_size, void* d_ws,
                              size_t ws_size, hipStream_t stream) {
    const float* x = (const float*)d_in[0];  // [B,S,IN]  f32
    const float* w = (const float*)d_in[1];  // [OUT,IN]  f32
    float* out = (float*)d_out;              // [B,S,OUT] f32

    const long long MK = (long long)in_sizes[0];
    const long long NK = (long long)in_sizes[1];
    const long long MN = (long long)out_size;
    const long long K =
        (long long)(sqrt((double)MK * (double)NK / (double)MN) + 0.5);
    const long long M = MK / K;  // 16384
    const long long N = NK / K;  // 2048

    unsigned short* qx = (unsigned short*)d_ws;  // M*K bf16
    unsigned short* qw = qx + MK;                // N*K bf16

    quant_fake_int8_kernel<<<(int)(MK / 1024), 256, 0, stream>>>(x, qx, MK);
    quant_fake_int8_kernel<<<(int)(NK / 1024), 256, 0, stream>>>(w, qw, NK);

    dim3 grid((int)((M / BM) * (N / BN)));  // 64 * 8 = 512
    gemm_bf16_quad<<<grid, 512, 0, stream>>>(qx, qw, out, (int)M, (int)N,
                                             (int)K);
}